// Round 1
// baseline (647.219 us; speedup 1.0000x reference)
//
#include <hip/hip_runtime.h>
#include <math.h>

// Decoder step: B=64, SEQ=1024, EN_H=DE_H=512, ATTN=256, EMBED=256, VOCAB=50000
// d_out layout: [out 64*50000][h1 64*512][h2 64*512][c1 64*512][c2 64*512]

__device__ __forceinline__ float sigf(float x) { return 1.f / (1.f + expf(-x)); }

// ---------------------------------------------------------------------------
// K1: gather emb, build X1=[dec|emb|ctx-slot], X2=[emb|ctxg-slot|h0[0]],
//     X3=[h1-slot|h0[1]], and decW = dec @ attn_W[512:1024]
// grid 64 (b), 256 threads
__global__ void k_prep(const int* __restrict__ cur, const float* __restrict__ h0,
                       const float* __restrict__ emb_table, const float* __restrict__ attn_W,
                       float* __restrict__ X1, float* __restrict__ X2, float* __restrict__ X3,
                       float* __restrict__ decW) {
    int b = blockIdx.x, t = threadIdx.x;
    __shared__ float dec_s[512];
    const float* dec = h0 + (size_t)(64 + b) * 512;   // h0[1][b] == h0[-1][b]
    for (int i = t; i < 512; i += 256) {
        float v = dec[i];
        dec_s[i] = v;
        X1[b * 1280 + i] = v;                          // X1[:,0:512) = dec
        X2[b * 1280 + 768 + i] = h0[(size_t)b * 512 + i]; // X2[:,768:1280) = h0[0]
        X3[b * 1024 + 512 + i] = v;                    // X3[:,512:1024) = h0[1]
    }
    int row = cur[b];
    float ev = emb_table[(size_t)row * 256 + t];
    X1[b * 1280 + 512 + t] = ev;                       // X1[:,512:768) = emb
    X2[b * 1280 + t] = ev;                             // X2[:,0:256)   = emb
    __syncthreads();
    // decW[b][a] = sum_k dec[k] * attn_W[512+k][a], a = t
    float acc = 0.f;
    for (int k = 0; k < 512; ++k)
        acc += dec_s[k] * attn_W[(size_t)(512 + k) * 256 + t];
    decW[b * 256 + t] = acc;
}

// ---------------------------------------------------------------------------
// K2: e[s][b] = sum_a tanh( enc[s,b,:]@attn_W_top[:,a] + decW[b][a] ) * v[a]
// One block per s (64 rows = all b), 256 threads, 64x64 reg-tiled f32 GEMM,
// K-chunks of 64, a-dim processed in 4 groups of 64, fused tanh*v reduce.
__global__ __launch_bounds__(256) void k_scores(const float* __restrict__ enc,
        const float* __restrict__ attn_W, const float* __restrict__ attn_v,
        const float* __restrict__ decW, float* __restrict__ e_out) {
    int s = blockIdx.x, t = threadIdx.x;
    int tr = t >> 4, tc = t & 15;                      // 16x16 thread grid
    __shared__ __align__(16) float As[64 * 68];        // [k][row]
    __shared__ __align__(16) float Ws[64 * 68];        // [k][col]
    __shared__ float red[256 * 4];
    const float* arow = enc + (size_t)s * 64 * 512;

    float acc[4][16];                                  // rows 4tr+j, cols ag*64+4tc+u
#pragma unroll
    for (int j = 0; j < 4; ++j)
#pragma unroll
        for (int i = 0; i < 16; ++i) acc[j][i] = 0.f;

    for (int kk = 0; kk < 512; kk += 64) {
        __syncthreads();
#pragma unroll
        for (int i = 0; i < 16; ++i) {                 // stage A: 64 rows x 64 k (transposed)
            int idx = i * 256 + t; int row = idx >> 6; int k = idx & 63;
            As[k * 68 + row] = arow[row * 512 + kk + k];
        }
        for (int ag = 0; ag < 4; ++ag) {
            __syncthreads();
#pragma unroll
            for (int i = 0; i < 16; ++i) {             // stage W: 64 k x 64 a
                int idx = i * 256 + t; int k = idx >> 6; int c = idx & 63;
                Ws[k * 68 + c] = attn_W[(size_t)(kk + k) * 256 + ag * 64 + c];
            }
            __syncthreads();
#pragma unroll 4
            for (int k = 0; k < 64; ++k) {
                float4 a = *(const float4*)&As[k * 68 + 4 * tr];
                float4 w = *(const float4*)&Ws[k * 68 + 4 * tc];
#pragma unroll
                for (int j = 0; j < 4; ++j) {
                    float aj = (j == 0) ? a.x : (j == 1) ? a.y : (j == 2) ? a.z : a.w;
                    acc[j][ag * 4 + 0] += aj * w.x;
                    acc[j][ag * 4 + 1] += aj * w.y;
                    acc[j][ag * 4 + 2] += aj * w.z;
                    acc[j][ag * 4 + 3] += aj * w.w;
                }
            }
        }
    }
    // epilogue: tanh(x + decW) * v, reduce over a
    int b0 = 4 * tr;
    float er[4] = {0.f, 0.f, 0.f, 0.f};
#pragma unroll
    for (int ag = 0; ag < 4; ++ag) {
#pragma unroll
        for (int u = 0; u < 4; ++u) {
            int a = ag * 64 + 4 * tc + u;
            float v = attn_v[a];
#pragma unroll
            for (int j = 0; j < 4; ++j) {
                float x = acc[j][ag * 4 + u] + decW[(b0 + j) * 256 + a];
                er[j] += tanhf(x) * v;
            }
        }
    }
    __syncthreads();
#pragma unroll
    for (int j = 0; j < 4; ++j) red[t * 4 + j] = er[j];
    __syncthreads();
    if (t < 64) {
        int trr = t >> 2, j = t & 3;
        float sum = 0.f;
#pragma unroll
        for (int tcc = 0; tcc < 16; ++tcc) sum += red[(trr * 16 + tcc) * 4 + j];
        e_out[s * 64 + 4 * trr + j] = sum;
    }
}

// ---------------------------------------------------------------------------
// K3: softmax over s (with mask) + ctx[b,h] = sum_s alpha[s,b]*enc[s,b,h]
// grid 256 = (b<<2)|hg, 128 threads, each thread owns one h of its 128-chunk
__global__ void k_softmax_ctx(const float* __restrict__ e, const float* __restrict__ mask,
                              const float* __restrict__ enc, float* __restrict__ X1) {
    int b = blockIdx.x >> 2, hg = blockIdx.x & 3;
    int t = threadIdx.x;                               // 128
    __shared__ float w[1024];
    __shared__ float red[128];
    float vals[8];
    float lmax = -1e30f;
#pragma unroll
    for (int si = 0; si < 8; ++si) {
        int s = si * 128 + t;
        float v = e[s * 64 + b];
        v = (mask[b * 1024 + s] > 0.f) ? v : -1e9f;
        vals[si] = v; lmax = fmaxf(lmax, v);
    }
    red[t] = lmax; __syncthreads();
    for (int o = 64; o > 0; o >>= 1) { if (t < o) red[t] = fmaxf(red[t], red[t + o]); __syncthreads(); }
    float m = red[0]; __syncthreads();
    float lsum = 0.f;
#pragma unroll
    for (int si = 0; si < 8; ++si) { float ex = expf(vals[si] - m); w[si * 128 + t] = ex; lsum += ex; }
    red[t] = lsum; __syncthreads();
    for (int o = 64; o > 0; o >>= 1) { if (t < o) red[t] += red[t + o]; __syncthreads(); }
    float inv = 1.f / red[0];
    __syncthreads();
    int h = hg * 128 + t;
    float acc = 0.f;
#pragma unroll 4
    for (int s = 0; s < 1024; ++s)
        acc += w[s] * enc[((size_t)s * 64 + b) * 512 + h];
    X1[b * 1280 + 768 + h] = acc * inv;                // raw ctx into X1
}

// ---------------------------------------------------------------------------
// Skinny GEMM (M=64) with K-split partials. Block: 1024 thr, tile 64x64,
// thread = 4 rows x 1 col. A staged transposed (reads broadcast, float4).
// k_gemm_cg: W is (K,N) row-major. grid (N/64, 4 ksplit), 5 chunks of 64.
__global__ __launch_bounds__(1024) void k_gemm_cg(const float* __restrict__ X,
        const float* __restrict__ Wkn, float* __restrict__ P) {
    int n0 = blockIdx.x * 64, sp = blockIdx.y;
    int t = threadIdx.x, tc = t & 63, tr = t >> 6;
    __shared__ __align__(16) float As[64 * 68];
    __shared__ __align__(16) float Wc[64 * 68];
    float acc[4] = {0.f, 0.f, 0.f, 0.f};
    for (int c = 0; c < 5; ++c) {
        int k0 = sp * 320 + c * 64;
        __syncthreads();
#pragma unroll
        for (int i = 0; i < 4; ++i) {
            int idx = i * 1024 + t; int row = idx >> 6; int k = idx & 63;
            As[k * 68 + row] = X[row * 1280 + k0 + k];
        }
#pragma unroll
        for (int i = 0; i < 4; ++i) {
            int idx = i * 1024 + t; int k = idx >> 6; int cc = idx & 63;
            Wc[k * 68 + cc] = Wkn[(size_t)(k0 + k) * 512 + n0 + cc];
        }
        __syncthreads();
#pragma unroll 8
        for (int k = 0; k < 64; ++k) {
            float4 a = *(const float4*)&As[k * 68 + 4 * tr];
            float wv = Wc[k * 68 + tc];
            acc[0] += a.x * wv; acc[1] += a.y * wv; acc[2] += a.z * wv; acc[3] += a.w * wv;
        }
    }
    float* Pp = P + (size_t)sp * 64 * 512;
#pragma unroll
    for (int j = 0; j < 4; ++j) Pp[(4 * tr + j) * 512 + n0 + tc] = acc[j];
}

// k_gemm_lstm: W = [W1 (N,K1) | W2 (N,K2)] both row-major (torch Linear layout).
// grid (32, 4), kchunks chunks of 64 per split.
__global__ __launch_bounds__(1024) void k_gemm_lstm(const float* __restrict__ X, int ldx,
        const float* __restrict__ W1, int K1, const float* __restrict__ W2, int K2,
        int kchunks, float* __restrict__ P) {
    int n0 = blockIdx.x * 64, sp = blockIdx.y;
    int t = threadIdx.x, tc = t & 63, tr = t >> 6;
    __shared__ __align__(16) float As[64 * 68];
    __shared__ __align__(16) float Wc[64 * 68];
    float acc[4] = {0.f, 0.f, 0.f, 0.f};
    for (int c = 0; c < kchunks; ++c) {
        int k0 = (sp * kchunks + c) * 64;
        __syncthreads();
#pragma unroll
        for (int i = 0; i < 4; ++i) {
            int idx = i * 1024 + t; int row = idx >> 6; int k = idx & 63;
            As[k * 68 + row] = X[row * ldx + k0 + k];
        }
#pragma unroll
        for (int i = 0; i < 4; ++i) {
            int idx = i * 1024 + t; int cc = idx >> 6; int k = idx & 63;
            int gk = k0 + k; int j = n0 + cc;
            float wv = (gk < K1) ? W1[(size_t)j * K1 + gk] : W2[(size_t)j * K2 + gk - K1];
            Wc[k * 68 + cc] = wv;
        }
        __syncthreads();
#pragma unroll 8
        for (int k = 0; k < 64; ++k) {
            float4 a = *(const float4*)&As[k * 68 + 4 * tr];
            float wv = Wc[k * 68 + tc];
            acc[0] += a.x * wv; acc[1] += a.y * wv; acc[2] += a.z * wv; acc[3] += a.w * wv;
        }
    }
    float* Pp = P + (size_t)sp * 64 * 2048;
#pragma unroll
    for (int j = 0; j < 4; ++j) Pp[(4 * tr + j) * 2048 + n0 + tc] = acc[j];
}

// ---------------------------------------------------------------------------
// context-gate finalize: gate = sigmoid(sum P + b); X2 ctxg slot = gate*ctx
__global__ void k_cg_fin(const float* __restrict__ P, const float* __restrict__ cg_b,
                         const float* __restrict__ X1, float* __restrict__ X2) {
    int idx = blockIdx.x * 256 + threadIdx.x;          // 32768
    int b = idx >> 9, h = idx & 511;
    float g = cg_b[h];
#pragma unroll
    for (int sp = 0; sp < 4; ++sp) g += P[sp * 32768 + idx];
    float gate = sigf(g);
    X2[b * 1280 + 256 + h] = gate * X1[b * 1280 + 768 + h];
}

// LSTM finalize: gates -> h_new, c_new
__global__ void k_lstm_fin(const float* __restrict__ P, const float* __restrict__ bih,
                           const float* __restrict__ bhh, const float* __restrict__ c0,
                           int layer, float* __restrict__ oh, float* __restrict__ oc,
                           float* __restrict__ X3out) {
    int idx = blockIdx.x * 256 + threadIdx.x;          // 32768
    int b = idx >> 9, h = idx & 511;
    float gi = bih[h] + bhh[h];
    float gf = bih[512 + h] + bhh[512 + h];
    float gg = bih[1024 + h] + bhh[1024 + h];
    float go = bih[1536 + h] + bhh[1536 + h];
#pragma unroll
    for (int sp = 0; sp < 4; ++sp) {
        const float* Pp = P + sp * 131072 + b * 2048;
        gi += Pp[h]; gf += Pp[512 + h]; gg += Pp[1024 + h]; go += Pp[1536 + h];
    }
    float cp = c0[layer * 32768 + b * 512 + h];
    float cn = sigf(gf) * cp + sigf(gi) * tanhf(gg);
    float hn = sigf(go) * tanhf(cn);
    oh[b * 512 + h] = hn;
    oc[b * 512 + h] = cn;
    if (X3out) X3out[b * 1024 + h] = hn;
}

// ---------------------------------------------------------------------------
// K5: out = h2 @ out_W + out_b  (out_W is (512, 50000) KN row-major)
__global__ __launch_bounds__(1024) void k_outproj(const float* __restrict__ h2,
        const float* __restrict__ out_W, const float* __restrict__ out_b,
        float* __restrict__ out) {
    int n0 = blockIdx.x * 64;
    int t = threadIdx.x, tc = t & 63, tr = t >> 6;
    __shared__ __align__(16) float As[64 * 68];
    __shared__ __align__(16) float Wc[64 * 68];
    float acc[4] = {0.f, 0.f, 0.f, 0.f};
    int n = n0 + tc;
    for (int kk = 0; kk < 512; kk += 64) {
        __syncthreads();
#pragma unroll
        for (int i = 0; i < 4; ++i) {
            int idx = i * 1024 + t; int row = idx >> 6; int k = idx & 63;
            As[k * 68 + row] = h2[row * 512 + kk + k];
        }
#pragma unroll
        for (int i = 0; i < 4; ++i) {
            int idx = i * 1024 + t; int k = idx >> 6; int cc = idx & 63;
            int nn = n0 + cc;
            Wc[k * 68 + cc] = (nn < 50000) ? out_W[(size_t)(kk + k) * 50000 + nn] : 0.f;
        }
        __syncthreads();
#pragma unroll 8
        for (int k = 0; k < 64; ++k) {
            float4 a = *(const float4*)&As[k * 68 + 4 * tr];
            float wv = Wc[k * 68 + tc];
            acc[0] += a.x * wv; acc[1] += a.y * wv; acc[2] += a.z * wv; acc[3] += a.w * wv;
        }
    }
    if (n < 50000) {
        float bias = out_b[n];
#pragma unroll
        for (int j = 0; j < 4; ++j)
            out[(size_t)(4 * tr + j) * 50000 + n] = acc[j] + bias;
    }
}

// ---------------------------------------------------------------------------
extern "C" void kernel_launch(void* const* d_in, const int* in_sizes, int n_in,
                              void* d_out, int out_size, void* d_ws, size_t ws_size,
                              hipStream_t stream) {
    const int*   cur       = (const int*)d_in[0];
    const float* h0        = (const float*)d_in[1];
    const float* c0        = (const float*)d_in[2];
    const float* enc       = (const float*)d_in[3];
    const float* mask      = (const float*)d_in[4];
    const float* emb_table = (const float*)d_in[5];
    const float* attn_W    = (const float*)d_in[6];
    const float* attn_v    = (const float*)d_in[7];
    const float* cg_W      = (const float*)d_in[8];
    const float* cg_b      = (const float*)d_in[9];
    const float* Wih0      = (const float*)d_in[10];
    const float* Whh0      = (const float*)d_in[11];
    const float* bih0      = (const float*)d_in[12];
    const float* bhh0      = (const float*)d_in[13];
    const float* Wih1      = (const float*)d_in[14];
    const float* Whh1      = (const float*)d_in[15];
    const float* bih1      = (const float*)d_in[16];
    const float* bhh1      = (const float*)d_in[17];
    const float* out_W     = (const float*)d_in[18];
    const float* out_b     = (const float*)d_in[19];
    float* out = (float*)d_out;

    float* w    = (float*)d_ws;
    float* X1   = w;                  // 64*1280 = 81920
    float* X2   = X1 + 81920;         // 64*1280
    float* X3   = X2 + 81920;         // 64*1024 = 65536
    float* decW = X3 + 65536;         // 64*256  = 16384
    float* eb   = decW + 16384;       // 1024*64 = 65536
    float* P    = eb + 65536;         // 4*64*2048 = 524288 (shared by cg/lstm)

    float* outH = out + 3200000;      // h1 then h2
    float* outC = out + 3265536;      // c1 then c2

    hipLaunchKernelGGL(k_prep, dim3(64), dim3(256), 0, stream,
                       cur, h0, emb_table, attn_W, X1, X2, X3, decW);
    hipLaunchKernelGGL(k_scores, dim3(1024), dim3(256), 0, stream,
                       enc, attn_W, attn_v, decW, eb);
    hipLaunchKernelGGL(k_softmax_ctx, dim3(256), dim3(128), 0, stream,
                       eb, mask, enc, X1);
    hipLaunchKernelGGL(k_gemm_cg, dim3(8, 4), dim3(1024), 0, stream, X1, cg_W, P);
    hipLaunchKernelGGL(k_cg_fin, dim3(128), dim3(256), 0, stream, P, cg_b, X1, X2);
    hipLaunchKernelGGL(k_gemm_lstm, dim3(32, 4), dim3(1024), 0, stream,
                       X2, 1280, Wih0, 768, Whh0, 512, 5, P);
    hipLaunchKernelGGL(k_lstm_fin, dim3(128), dim3(256), 0, stream,
                       P, bih0, bhh0, c0, 0, outH, outC, X3);
    hipLaunchKernelGGL(k_gemm_lstm, dim3(32, 4), dim3(1024), 0, stream,
                       X3, 1024, Wih1, 512, Whh1, 512, 4, P);
    hipLaunchKernelGGL(k_lstm_fin, dim3(128), dim3(256), 0, stream,
                       P, bih1, bhh1, c0, 1, outH + 32768, outC + 32768, (float*)nullptr);
    hipLaunchKernelGGL(k_outproj, dim3(782), dim3(1024), 0, stream,
                       outH + 32768, out_W, out_b, out);
}

// Round 2
// 317.701 us; speedup vs baseline: 2.0372x; 2.0372x over previous
//
#include <hip/hip_runtime.h>
#include <math.h>

// Decoder step: B=64, SEQ=1024, EN_H=DE_H=512, ATTN=256, EMBED=256, VOCAB=50000
// d_out layout: [out 64*50000][h1 64*512][h2 64*512][c1 64*512][c2 64*512]

typedef __attribute__((ext_vector_type(8))) short short8;
typedef __attribute__((ext_vector_type(4))) float f32x4;

__device__ __forceinline__ float sigf(float x) { return 1.f / (1.f + expf(-x)); }

__device__ __forceinline__ unsigned short f2bf(float f) {
    unsigned int u = __builtin_bit_cast(unsigned int, f);
    unsigned int r = (u + 0x7fffu + ((u >> 16) & 1u)) >> 16;   // RNE
    return (unsigned short)r;
}

__device__ __forceinline__ float tanh_fast(float x) {
    float t = __expf(2.f * x);                    // inf for big x -> 1; 0 for very neg -> -1
    return 1.f - 2.f * __builtin_amdgcn_rcpf(1.f + t);
}

// ---------------------------------------------------------------------------
// K0: transpose+convert attn_W top half (512x256 f32, KN) -> Wt (256x512 bf16, NK)
// grid (8,4) of 64x64 tiles, 256 threads
__global__ void k_convW(const float* __restrict__ W, unsigned short* __restrict__ Wt) {
    __shared__ float tile[64][65];
    int kb = blockIdx.x * 64, nb = blockIdx.y * 64;
    int t = threadIdx.x;
    int r0 = t >> 6, c = t & 63;
#pragma unroll
    for (int i = 0; i < 16; ++i) {
        int r = i * 4 + r0;
        tile[r][c] = W[(size_t)(kb + r) * 256 + nb + c];
    }
    __syncthreads();
#pragma unroll
    for (int i = 0; i < 16; ++i) {
        int r = i * 4 + r0;
        Wt[(size_t)(nb + r) * 512 + kb + c] = f2bf(tile[c][r]);
    }
}

// ---------------------------------------------------------------------------
// K1: gather emb, build X1=[dec|emb|ctx-slot], X2=[emb|ctxg-slot|h0[0]],
//     X3=[h1-slot|h0[1]], and decW = dec @ attn_W[512:1024]
// grid 64 (b), 256 threads
__global__ void k_prep(const int* __restrict__ cur, const float* __restrict__ h0,
                       const float* __restrict__ emb_table, const float* __restrict__ attn_W,
                       float* __restrict__ X1, float* __restrict__ X2, float* __restrict__ X3,
                       float* __restrict__ decW) {
    int b = blockIdx.x, t = threadIdx.x;
    __shared__ float dec_s[512];
    const float* dec = h0 + (size_t)(64 + b) * 512;   // h0[1][b] == h0[-1][b]
    for (int i = t; i < 512; i += 256) {
        float v = dec[i];
        dec_s[i] = v;
        X1[b * 1280 + i] = v;                          // X1[:,0:512) = dec
        X2[b * 1280 + 768 + i] = h0[(size_t)b * 512 + i]; // X2[:,768:1280) = h0[0]
        X3[b * 1024 + 512 + i] = v;                    // X3[:,512:1024) = h0[1]
    }
    int row = cur[b];
    float ev = emb_table[(size_t)row * 256 + t];
    X1[b * 1280 + 512 + t] = ev;                       // X1[:,512:768) = emb
    X2[b * 1280 + t] = ev;                             // X2[:,0:256)   = emb
    __syncthreads();
    // decW[b][a] = sum_k dec[k] * attn_W[512+k][a], a = t
    float acc = 0.f;
    for (int k = 0; k < 512; ++k)
        acc += dec_s[k] * attn_W[(size_t)(512 + k) * 256 + t];
    decW[b * 256 + t] = acc;
}

// ---------------------------------------------------------------------------
// K2 (MFMA): e[s][b] = sum_a tanh( enc[s,b,:]@Wt[a,:] + decW[b][a] ) * v[a]
// 1 block per s, 256 thr (4 waves). Tile M=64 x N=256 x K=512, bf16 16x16x32.
// Wave w owns all 64 rows x cols [w*64, w*64+64): acc[4 rowtile][4 coltile].
// LDS: sA 64x64 bf16 (8KB) + sB 256x64 bf16 (32KB), XOR-swizzled 16B slots.
__global__ __launch_bounds__(256) void k_scores_mfma(
        const float* __restrict__ enc, const unsigned short* __restrict__ Wt,
        const float* __restrict__ attn_v, const float* __restrict__ decW,
        float* __restrict__ e_out) {
    int s = blockIdx.x, t = threadIdx.x;
    __shared__ __align__(16) unsigned short sA[4096];    // 8 KB
    __shared__ __align__(16) unsigned short sB[16384];   // 32 KB
    const float* arow = enc + (size_t)s * 64 * 512;
    int w = t >> 6, l = t & 63, li = l & 15, lg = l >> 4;
    int sw = (li & 7) << 4;

    f32x4 acc[4][4];
#pragma unroll
    for (int rt = 0; rt < 4; ++rt)
#pragma unroll
        for (int ct = 0; ct < 4; ++ct) acc[rt][ct] = (f32x4){0.f, 0.f, 0.f, 0.f};

    for (int kk = 0; kk < 512; kk += 64) {
        __syncthreads();
        // stage A: 64 rows x 64 k, f32 -> bf16 in-register
#pragma unroll
        for (int i = 0; i < 2; ++i) {
            int idx = i * 256 + t, row = idx >> 3, kg = idx & 7;
            const float* g = arow + row * 512 + kk + kg * 8;
            float4 p0 = *(const float4*)g;
            float4 p1 = *(const float4*)(g + 4);
            uint4 wv;
            wv.x = f2bf(p0.x) | ((unsigned)f2bf(p0.y) << 16);
            wv.y = f2bf(p0.z) | ((unsigned)f2bf(p0.w) << 16);
            wv.z = f2bf(p1.x) | ((unsigned)f2bf(p1.y) << 16);
            wv.w = f2bf(p1.z) | ((unsigned)f2bf(p1.w) << 16);
            int byte = (row * 128 + kg * 16) ^ ((row & 7) << 4);
            *(uint4*)((char*)sA + byte) = wv;
        }
        // stage B: 256 cols x 64 k from pre-converted Wt (bf16, NK row-major)
#pragma unroll
        for (int i = 0; i < 8; ++i) {
            int idx = i * 256 + t, n = idx >> 3, kg = idx & 7;
            uint4 wv = *(const uint4*)(Wt + (size_t)n * 512 + kk + kg * 8);
            int byte = (n * 128 + kg * 16) ^ ((n & 7) << 4);
            *(uint4*)((char*)sB + byte) = wv;
        }
        __syncthreads();
#pragma unroll
        for (int ks = 0; ks < 2; ++ks) {
            short8 af[4], bf[4];
#pragma unroll
            for (int rt = 0; rt < 4; ++rt) {
                int row = rt * 16 + li;
                af[rt] = *(short8*)((char*)sA + ((row * 128 + ks * 64 + lg * 16) ^ sw));
            }
#pragma unroll
            for (int ct = 0; ct < 4; ++ct) {
                int n = w * 64 + ct * 16 + li;
                bf[ct] = *(short8*)((char*)sB + ((n * 128 + ks * 64 + lg * 16) ^ sw));
            }
#pragma unroll
            for (int rt = 0; rt < 4; ++rt)
#pragma unroll
                for (int ct = 0; ct < 4; ++ct)
                    acc[rt][ct] = __builtin_amdgcn_mfma_f32_16x16x32_bf16(
                        af[rt], bf[ct], acc[rt][ct], 0, 0, 0);
        }
    }
    // epilogue: tanh(acc + decW[b][a]) * v[a], reduce over a
    float er[4][4];   // [rowtile][reg]
#pragma unroll
    for (int rt = 0; rt < 4; ++rt)
#pragma unroll
        for (int r = 0; r < 4; ++r) er[rt][r] = 0.f;
#pragma unroll
    for (int ct = 0; ct < 4; ++ct) {
        int a = w * 64 + ct * 16 + li;
        float v = attn_v[a];
#pragma unroll
        for (int rt = 0; rt < 4; ++rt) {
#pragma unroll
            for (int r = 0; r < 4; ++r) {
                int row = rt * 16 + lg * 4 + r;     // batch index b
                float x = acc[rt][ct][r] + decW[row * 256 + a];
                er[rt][r] += tanh_fast(x) * v;
            }
        }
    }
    // reduce across the 16 lanes of each lg-group (xor bits 0..3 touch li only)
#pragma unroll
    for (int off = 1; off < 16; off <<= 1)
#pragma unroll
        for (int rt = 0; rt < 4; ++rt)
#pragma unroll
            for (int r = 0; r < 4; ++r)
                er[rt][r] += __shfl_xor(er[rt][r], off, 64);
    __syncthreads();                 // done with sA: reuse as partial buffer
    float* part = (float*)sA;        // [4 waves][64 rows]
    if (li == 0) {
#pragma unroll
        for (int rt = 0; rt < 4; ++rt)
#pragma unroll
            for (int r = 0; r < 4; ++r)
                part[w * 64 + rt * 16 + lg * 4 + r] = er[rt][r];
    }
    __syncthreads();
    if (t < 64)
        e_out[s * 64 + t] = part[t] + part[64 + t] + part[128 + t] + part[192 + t];
}

// ---------------------------------------------------------------------------
// K3: softmax over s (with mask) + ctx[b,h] = sum_s alpha[s,b]*enc[s,b,h]
// grid 256 = (b<<2)|hg, 128 threads, each thread owns one h of its 128-chunk
__global__ void k_softmax_ctx(const float* __restrict__ e, const float* __restrict__ mask,
                              const float* __restrict__ enc, float* __restrict__ X1) {
    int b = blockIdx.x >> 2, hg = blockIdx.x & 3;
    int t = threadIdx.x;                               // 128
    __shared__ float w[1024];
    __shared__ float red[128];
    float vals[8];
    float lmax = -1e30f;
#pragma unroll
    for (int si = 0; si < 8; ++si) {
        int s = si * 128 + t;
        float v = e[s * 64 + b];
        v = (mask[b * 1024 + s] > 0.f) ? v : -1e9f;
        vals[si] = v; lmax = fmaxf(lmax, v);
    }
    red[t] = lmax; __syncthreads();
    for (int o = 64; o > 0; o >>= 1) { if (t < o) red[t] = fmaxf(red[t], red[t + o]); __syncthreads(); }
    float m = red[0]; __syncthreads();
    float lsum = 0.f;
#pragma unroll
    for (int si = 0; si < 8; ++si) { float ex = expf(vals[si] - m); w[si * 128 + t] = ex; lsum += ex; }
    red[t] = lsum; __syncthreads();
    for (int o = 64; o > 0; o >>= 1) { if (t < o) red[t] += red[t + o]; __syncthreads(); }
    float inv = 1.f / red[0];
    __syncthreads();
    int h = hg * 128 + t;
    float acc = 0.f;
#pragma unroll 4
    for (int s = 0; s < 1024; ++s)
        acc += w[s] * enc[((size_t)s * 64 + b) * 512 + h];
    X1[b * 1280 + 768 + h] = acc * inv;                // raw ctx into X1
}

// ---------------------------------------------------------------------------
// Skinny GEMM (M=64) with K-split partials. Block: 1024 thr, tile 64x64,
// thread = 4 rows x 1 col. A staged transposed (reads broadcast, float4).
// k_gemm_cg: W is (K,N) row-major. grid (N/64, 4 ksplit), 5 chunks of 64.
__global__ __launch_bounds__(1024) void k_gemm_cg(const float* __restrict__ X,
        const float* __restrict__ Wkn, float* __restrict__ P) {
    int n0 = blockIdx.x * 64, sp = blockIdx.y;
    int t = threadIdx.x, tc = t & 63, tr = t >> 6;
    __shared__ __align__(16) float As[64 * 68];
    __shared__ __align__(16) float Wc[64 * 68];
    float acc[4] = {0.f, 0.f, 0.f, 0.f};
    for (int c = 0; c < 5; ++c) {
        int k0 = sp * 320 + c * 64;
        __syncthreads();
#pragma unroll
        for (int i = 0; i < 4; ++i) {
            int idx = i * 1024 + t; int row = idx >> 6; int k = idx & 63;
            As[k * 68 + row] = X[row * 1280 + k0 + k];
        }
#pragma unroll
        for (int i = 0; i < 4; ++i) {
            int idx = i * 1024 + t; int k = idx >> 6; int cc = idx & 63;
            Wc[k * 68 + cc] = Wkn[(size_t)(k0 + k) * 512 + n0 + cc];
        }
        __syncthreads();
#pragma unroll 8
        for (int k = 0; k < 64; ++k) {
            float4 a = *(const float4*)&As[k * 68 + 4 * tr];
            float wv = Wc[k * 68 + tc];
            acc[0] += a.x * wv; acc[1] += a.y * wv; acc[2] += a.z * wv; acc[3] += a.w * wv;
        }
    }
    float* Pp = P + (size_t)sp * 64 * 512;
#pragma unroll
    for (int j = 0; j < 4; ++j) Pp[(4 * tr + j) * 512 + n0 + tc] = acc[j];
}

// k_gemm_lstm: W = [W1 (N,K1) | W2 (N,K2)] both row-major (torch Linear layout).
// grid (32, 4), kchunks chunks of 64 per split.
__global__ __launch_bounds__(1024) void k_gemm_lstm(const float* __restrict__ X, int ldx,
        const float* __restrict__ W1, int K1, const float* __restrict__ W2, int K2,
        int kchunks, float* __restrict__ P) {
    int n0 = blockIdx.x * 64, sp = blockIdx.y;
    int t = threadIdx.x, tc = t & 63, tr = t >> 6;
    __shared__ __align__(16) float As[64 * 68];
    __shared__ __align__(16) float Wc[64 * 68];
    float acc[4] = {0.f, 0.f, 0.f, 0.f};
    for (int c = 0; c < kchunks; ++c) {
        int k0 = (sp * kchunks + c) * 64;
        __syncthreads();
#pragma unroll
        for (int i = 0; i < 4; ++i) {
            int idx = i * 1024 + t; int row = idx >> 6; int k = idx & 63;
            As[k * 68 + row] = X[row * ldx + k0 + k];
        }
#pragma unroll
        for (int i = 0; i < 4; ++i) {
            int idx = i * 1024 + t; int cc = idx >> 6; int k = idx & 63;
            int gk = k0 + k; int j = n0 + cc;
            float wv = (gk < K1) ? W1[(size_t)j * K1 + gk] : W2[(size_t)j * K2 + gk - K1];
            Wc[k * 68 + cc] = wv;
        }
        __syncthreads();
#pragma unroll 8
        for (int k = 0; k < 64; ++k) {
            float4 a = *(const float4*)&As[k * 68 + 4 * tr];
            float wv = Wc[k * 68 + tc];
            acc[0] += a.x * wv; acc[1] += a.y * wv; acc[2] += a.z * wv; acc[3] += a.w * wv;
        }
    }
    float* Pp = P + (size_t)sp * 64 * 2048;
#pragma unroll
    for (int j = 0; j < 4; ++j) Pp[(4 * tr + j) * 2048 + n0 + tc] = acc[j];
}

// ---------------------------------------------------------------------------
// context-gate finalize: gate = sigmoid(sum P + b); X2 ctxg slot = gate*ctx
__global__ void k_cg_fin(const float* __restrict__ P, const float* __restrict__ cg_b,
                         const float* __restrict__ X1, float* __restrict__ X2) {
    int idx = blockIdx.x * 256 + threadIdx.x;          // 32768
    int b = idx >> 9, h = idx & 511;
    float g = cg_b[h];
#pragma unroll
    for (int sp = 0; sp < 4; ++sp) g += P[sp * 32768 + idx];
    float gate = sigf(g);
    X2[b * 1280 + 256 + h] = gate * X1[b * 1280 + 768 + h];
}

// LSTM finalize: gates -> h_new, c_new
__global__ void k_lstm_fin(const float* __restrict__ P, const float* __restrict__ bih,
                           const float* __restrict__ bhh, const float* __restrict__ c0,
                           int layer, float* __restrict__ oh, float* __restrict__ oc,
                           float* __restrict__ X3out) {
    int idx = blockIdx.x * 256 + threadIdx.x;          // 32768
    int b = idx >> 9, h = idx & 511;
    float gi = bih[h] + bhh[h];
    float gf = bih[512 + h] + bhh[512 + h];
    float gg = bih[1024 + h] + bhh[1024 + h];
    float go = bih[1536 + h] + bhh[1536 + h];
#pragma unroll
    for (int sp = 0; sp < 4; ++sp) {
        const float* Pp = P + sp * 131072 + b * 2048;
        gi += Pp[h]; gf += Pp[512 + h]; gg += Pp[1024 + h]; go += Pp[1536 + h];
    }
    float cp = c0[layer * 32768 + b * 512 + h];
    float cn = sigf(gf) * cp + sigf(gi) * tanhf(gg);
    float hn = sigf(go) * tanhf(cn);
    oh[b * 512 + h] = hn;
    oc[b * 512 + h] = cn;
    if (X3out) X3out[b * 1024 + h] = hn;
}

// ---------------------------------------------------------------------------
// K5: out = h2 @ out_W + out_b  (out_W is (512, 50000) KN row-major)
__global__ __launch_bounds__(1024) void k_outproj(const float* __restrict__ h2,
        const float* __restrict__ out_W, const float* __restrict__ out_b,
        float* __restrict__ out) {
    int n0 = blockIdx.x * 64;
    int t = threadIdx.x, tc = t & 63, tr = t >> 6;
    __shared__ __align__(16) float As[64 * 68];
    __shared__ __align__(16) float Wc[64 * 68];
    float acc[4] = {0.f, 0.f, 0.f, 0.f};
    int n = n0 + tc;
    for (int kk = 0; kk < 512; kk += 64) {
        __syncthreads();
#pragma unroll
        for (int i = 0; i < 4; ++i) {
            int idx = i * 1024 + t; int row = idx >> 6; int k = idx & 63;
            As[k * 68 + row] = h2[row * 512 + kk + k];
        }
#pragma unroll
        for (int i = 0; i < 4; ++i) {
            int idx = i * 1024 + t; int k = idx >> 6; int cc = idx & 63;
            int nn = n0 + cc;
            Wc[k * 68 + cc] = (nn < 50000) ? out_W[(size_t)(kk + k) * 50000 + nn] : 0.f;
        }
        __syncthreads();
#pragma unroll 8
        for (int k = 0; k < 64; ++k) {
            float4 a = *(const float4*)&As[k * 68 + 4 * tr];
            float wv = Wc[k * 68 + tc];
            acc[0] += a.x * wv; acc[1] += a.y * wv; acc[2] += a.z * wv; acc[3] += a.w * wv;
        }
    }
    if (n < 50000) {
        float bias = out_b[n];
#pragma unroll
        for (int j = 0; j < 4; ++j)
            out[(size_t)(4 * tr + j) * 50000 + n] = acc[j] + bias;
    }
}

// ---------------------------------------------------------------------------
extern "C" void kernel_launch(void* const* d_in, const int* in_sizes, int n_in,
                              void* d_out, int out_size, void* d_ws, size_t ws_size,
                              hipStream_t stream) {
    const int*   cur       = (const int*)d_in[0];
    const float* h0        = (const float*)d_in[1];
    const float* c0        = (const float*)d_in[2];
    const float* enc       = (const float*)d_in[3];
    const float* mask      = (const float*)d_in[4];
    const float* emb_table = (const float*)d_in[5];
    const float* attn_W    = (const float*)d_in[6];
    const float* attn_v    = (const float*)d_in[7];
    const float* cg_W      = (const float*)d_in[8];
    const float* cg_b      = (const float*)d_in[9];
    const float* Wih0      = (const float*)d_in[10];
    const float* Whh0      = (const float*)d_in[11];
    const float* bih0      = (const float*)d_in[12];
    const float* bhh0      = (const float*)d_in[13];
    const float* Wih1      = (const float*)d_in[14];
    const float* Whh1      = (const float*)d_in[15];
    const float* bih1      = (const float*)d_in[16];
    const float* bhh1      = (const float*)d_in[17];
    const float* out_W     = (const float*)d_in[18];
    const float* out_b     = (const float*)d_in[19];
    float* out = (float*)d_out;

    float* w    = (float*)d_ws;
    float* X1   = w;                  // 64*1280 = 81920
    float* X2   = X1 + 81920;         // 64*1280
    float* X3   = X2 + 81920;         // 64*1024 = 65536
    float* decW = X3 + 65536;         // 64*256  = 16384
    float* eb   = decW + 16384;       // 1024*64 = 65536
    float* P    = eb + 65536;         // 4*64*2048 = 524288 (shared by cg/lstm)
    // Wt (bf16 256x512 = 256KB) parked at front of P: consumed by k_scores
    // before the first GEMM writes P.
    unsigned short* Wt = (unsigned short*)P;

    float* outH = out + 3200000;      // h1 then h2
    float* outC = out + 3265536;      // c1 then c2

    hipLaunchKernelGGL(k_convW, dim3(8, 4), dim3(256), 0, stream, attn_W, Wt);
    hipLaunchKernelGGL(k_prep, dim3(64), dim3(256), 0, stream,
                       cur, h0, emb_table, attn_W, X1, X2, X3, decW);
    hipLaunchKernelGGL(k_scores_mfma, dim3(1024), dim3(256), 0, stream,
                       enc, Wt, attn_v, decW, eb);
    hipLaunchKernelGGL(k_softmax_ctx, dim3(256), dim3(128), 0, stream,
                       eb, mask, enc, X1);
    hipLaunchKernelGGL(k_gemm_cg, dim3(8, 4), dim3(1024), 0, stream, X1, cg_W, P);
    hipLaunchKernelGGL(k_cg_fin, dim3(128), dim3(256), 0, stream, P, cg_b, X1, X2);
    hipLaunchKernelGGL(k_gemm_lstm, dim3(32, 4), dim3(1024), 0, stream,
                       X2, 1280, Wih0, 768, Whh0, 512, 5, P);
    hipLaunchKernelGGL(k_lstm_fin, dim3(128), dim3(256), 0, stream,
                       P, bih0, bhh0, c0, 0, outH, outC, X3);
    hipLaunchKernelGGL(k_gemm_lstm, dim3(32, 4), dim3(1024), 0, stream,
                       X3, 1024, Wih1, 512, Whh1, 512, 4, P);
    hipLaunchKernelGGL(k_lstm_fin, dim3(128), dim3(256), 0, stream,
                       P, bih1, bhh1, c0, 1, outH + 32768, outC + 32768, (float*)nullptr);
    hipLaunchKernelGGL(k_outproj, dim3(782), dim3(1024), 0, stream,
                       outH + 32768, out_W, out_b, out);
}

// Round 3
// 187.580 us; speedup vs baseline: 3.4504x; 1.6937x over previous
//
#include <hip/hip_runtime.h>
#include <math.h>

// Decoder step: B=64, SEQ=1024, EN_H=DE_H=512, ATTN=256, EMBED=256, VOCAB=50000
// d_out layout: [out 64*50000][h1 64*512][h2 64*512][c1 64*512][c2 64*512]

typedef __attribute__((ext_vector_type(8))) short short8;
typedef __attribute__((ext_vector_type(4))) float f32x4;

__device__ __forceinline__ float sigf(float x) { return 1.f / (1.f + expf(-x)); }

__device__ __forceinline__ unsigned short f2bf(float f) {
    unsigned int u = __builtin_bit_cast(unsigned int, f);
    unsigned int r = (u + 0x7fffu + ((u >> 16) & 1u)) >> 16;   // RNE
    return (unsigned short)r;
}

__device__ __forceinline__ float tanh_fast(float x) {
    float t = __expf(2.f * x);
    return 1.f - 2.f * __builtin_amdgcn_rcpf(1.f + t);
}

// ---------------------------------------------------------------------------
// K0: transpose+convert attn_W top half (512x256 f32, KN) -> Wt (256x512 bf16, NK)
__global__ void k_convW(const float* __restrict__ W, unsigned short* __restrict__ Wt) {
    __shared__ float tile[64][65];
    int kb = blockIdx.x * 64, nb = blockIdx.y * 64;
    int t = threadIdx.x;
    int r0 = t >> 6, c = t & 63;
#pragma unroll
    for (int i = 0; i < 16; ++i) {
        int r = i * 4 + r0;
        tile[r][c] = W[(size_t)(kb + r) * 256 + nb + c];
    }
    __syncthreads();
#pragma unroll
    for (int i = 0; i < 16; ++i) {
        int r = i * 4 + r0;
        Wt[(size_t)(nb + r) * 512 + kb + c] = f2bf(tile[c][r]);
    }
}

// ---------------------------------------------------------------------------
// K1: gather emb, build X1/X2/X3 slots, decW = dec @ attn_W[512:1024]
__global__ void k_prep(const int* __restrict__ cur, const float* __restrict__ h0,
                       const float* __restrict__ emb_table, const float* __restrict__ attn_W,
                       float* __restrict__ X1, float* __restrict__ X2, float* __restrict__ X3,
                       float* __restrict__ decW) {
    int b = blockIdx.x, t = threadIdx.x;
    __shared__ float dec_s[512];
    const float* dec = h0 + (size_t)(64 + b) * 512;   // h0[1][b] == h0[-1][b]
    for (int i = t; i < 512; i += 256) {
        float v = dec[i];
        dec_s[i] = v;
        X1[b * 1280 + i] = v;
        X2[b * 1280 + 768 + i] = h0[(size_t)b * 512 + i];
        X3[b * 1024 + 512 + i] = v;
    }
    int row = cur[b];
    float ev = emb_table[(size_t)row * 256 + t];
    X1[b * 1280 + 512 + t] = ev;
    X2[b * 1280 + t] = ev;
    __syncthreads();
    float acc = 0.f;
    for (int k = 0; k < 512; ++k)
        acc += dec_s[k] * attn_W[(size_t)(512 + k) * 256 + t];
    decW[b * 256 + t] = acc;
}

// ---------------------------------------------------------------------------
// K2 (MFMA): e[b][s] = sum_a tanh( enc[s,b,:]@Wt[a,:] + decW[b][a] ) * v[a]
__global__ __launch_bounds__(256) void k_scores_mfma(
        const float* __restrict__ enc, const unsigned short* __restrict__ Wt,
        const float* __restrict__ attn_v, const float* __restrict__ decW,
        float* __restrict__ e_out) {
    int s = blockIdx.x, t = threadIdx.x;
    __shared__ __align__(16) unsigned short sA[4096];    // 8 KB
    __shared__ __align__(16) unsigned short sB[16384];   // 32 KB
    const float* arow = enc + (size_t)s * 64 * 512;
    int w = t >> 6, l = t & 63, li = l & 15, lg = l >> 4;
    int sw = (li & 7) << 4;

    f32x4 acc[4][4];
#pragma unroll
    for (int rt = 0; rt < 4; ++rt)
#pragma unroll
        for (int ct = 0; ct < 4; ++ct) acc[rt][ct] = (f32x4){0.f, 0.f, 0.f, 0.f};

    for (int kk = 0; kk < 512; kk += 64) {
        __syncthreads();
#pragma unroll
        for (int i = 0; i < 2; ++i) {
            int idx = i * 256 + t, row = idx >> 3, kg = idx & 7;
            const float* g = arow + row * 512 + kk + kg * 8;
            float4 p0 = *(const float4*)g;
            float4 p1 = *(const float4*)(g + 4);
            uint4 wv;
            wv.x = f2bf(p0.x) | ((unsigned)f2bf(p0.y) << 16);
            wv.y = f2bf(p0.z) | ((unsigned)f2bf(p0.w) << 16);
            wv.z = f2bf(p1.x) | ((unsigned)f2bf(p1.y) << 16);
            wv.w = f2bf(p1.z) | ((unsigned)f2bf(p1.w) << 16);
            int byte = (row * 128 + kg * 16) ^ ((row & 7) << 4);
            *(uint4*)((char*)sA + byte) = wv;
        }
#pragma unroll
        for (int i = 0; i < 8; ++i) {
            int idx = i * 256 + t, n = idx >> 3, kg = idx & 7;
            uint4 wv = *(const uint4*)(Wt + (size_t)n * 512 + kk + kg * 8);
            int byte = (n * 128 + kg * 16) ^ ((n & 7) << 4);
            *(uint4*)((char*)sB + byte) = wv;
        }
        __syncthreads();
#pragma unroll
        for (int ks = 0; ks < 2; ++ks) {
            short8 af[4], bf[4];
#pragma unroll
            for (int rt = 0; rt < 4; ++rt) {
                int row = rt * 16 + li;
                af[rt] = *(short8*)((char*)sA + ((row * 128 + ks * 64 + lg * 16) ^ sw));
            }
#pragma unroll
            for (int ct = 0; ct < 4; ++ct) {
                int n = w * 64 + ct * 16 + li;
                bf[ct] = *(short8*)((char*)sB + ((n * 128 + ks * 64 + lg * 16) ^ sw));
            }
#pragma unroll
            for (int rt = 0; rt < 4; ++rt)
#pragma unroll
                for (int ct = 0; ct < 4; ++ct)
                    acc[rt][ct] = __builtin_amdgcn_mfma_f32_16x16x32_bf16(
                        af[rt], bf[ct], acc[rt][ct], 0, 0, 0);
        }
    }
    float er[4][4];
#pragma unroll
    for (int rt = 0; rt < 4; ++rt)
#pragma unroll
        for (int r = 0; r < 4; ++r) er[rt][r] = 0.f;
#pragma unroll
    for (int ct = 0; ct < 4; ++ct) {
        int a = w * 64 + ct * 16 + li;
        float v = attn_v[a];
#pragma unroll
        for (int rt = 0; rt < 4; ++rt) {
#pragma unroll
            for (int r = 0; r < 4; ++r) {
                int row = rt * 16 + lg * 4 + r;
                float x = acc[rt][ct][r] + decW[row * 256 + a];
                er[rt][r] += tanh_fast(x) * v;
            }
        }
    }
#pragma unroll
    for (int off = 1; off < 16; off <<= 1)
#pragma unroll
        for (int rt = 0; rt < 4; ++rt)
#pragma unroll
            for (int r = 0; r < 4; ++r)
                er[rt][r] += __shfl_xor(er[rt][r], off, 64);
    __syncthreads();
    float* part = (float*)sA;
    if (li == 0) {
#pragma unroll
        for (int rt = 0; rt < 4; ++rt)
#pragma unroll
            for (int r = 0; r < 4; ++r)
                part[w * 64 + rt * 16 + lg * 4 + r] = er[rt][r];
    }
    __syncthreads();
    if (t < 64)   // e stored [b][s] for coalesced softmax/ctx reads
        e_out[t * 1024 + s] = part[t] + part[64 + t] + part[128 + t] + part[192 + t];
}

// ---------------------------------------------------------------------------
// K3a: masked softmax over s per batch row, in-place on e[b][s]
__global__ void k_softmax(float* __restrict__ ebuf, const float* __restrict__ mask) {
    int b = blockIdx.x, t = threadIdx.x;               // 256 thr
    __shared__ float red[8];
    float v[4];
    float lmax = -1e30f;
#pragma unroll
    for (int si = 0; si < 4; ++si) {
        int s = si * 256 + t;
        float x = ebuf[b * 1024 + s];
        x = (mask[b * 1024 + s] > 0.f) ? x : -1e9f;
        v[si] = x; lmax = fmaxf(lmax, x);
    }
#pragma unroll
    for (int off = 32; off > 0; off >>= 1) lmax = fmaxf(lmax, __shfl_xor(lmax, off, 64));
    if ((t & 63) == 0) red[t >> 6] = lmax;
    __syncthreads();
    float m = fmaxf(fmaxf(red[0], red[1]), fmaxf(red[2], red[3]));
    float e4[4], lsum = 0.f;
#pragma unroll
    for (int si = 0; si < 4; ++si) { e4[si] = __expf(v[si] - m); lsum += e4[si]; }
#pragma unroll
    for (int off = 32; off > 0; off >>= 1) lsum += __shfl_xor(lsum, off, 64);
    if ((t & 63) == 0) red[4 + (t >> 6)] = lsum;
    __syncthreads();
    float inv = 1.f / (red[4] + red[5] + red[6] + red[7]);
#pragma unroll
    for (int si = 0; si < 4; ++si)
        ebuf[b * 1024 + si * 256 + t] = e4[si] * inv;
}

// K3b: ctx partials: block (sc,b) accumulates 128 s-slabs of enc
__global__ __launch_bounds__(512) void k_ctx_partial(const float* __restrict__ alpha,
        const float* __restrict__ enc, float* __restrict__ ctxP) {
    int b = blockIdx.x & 63, sc = blockIdx.x >> 6;
    int t = threadIdx.x;                               // 512 = one h each
    __shared__ float al[128];
    if (t < 128) al[t] = alpha[b * 1024 + sc * 128 + t];
    __syncthreads();
    const float* base = enc + (((size_t)sc * 128 * 64) + b) * 512 + t;
    float a0 = 0.f, a1 = 0.f, a2 = 0.f, a3 = 0.f;
    for (int s = 0; s < 128; s += 4) {
        float x0 = base[(size_t)(s + 0) * 32768];
        float x1 = base[(size_t)(s + 1) * 32768];
        float x2 = base[(size_t)(s + 2) * 32768];
        float x3 = base[(size_t)(s + 3) * 32768];
        a0 += al[s] * x0; a1 += al[s + 1] * x1; a2 += al[s + 2] * x2; a3 += al[s + 3] * x3;
    }
    ctxP[((size_t)sc * 64 + b) * 512 + t] = a0 + a1 + a2 + a3;
}

// K3c: reduce 8 partials -> ctx into X1 slot
__global__ void k_ctx_reduce(const float* __restrict__ ctxP, float* __restrict__ X1) {
    int idx = blockIdx.x * 256 + threadIdx.x;          // 32768
    int b = idx >> 9, h = idx & 511;
    float s = 0.f;
#pragma unroll
    for (int sc = 0; sc < 8; ++sc) s += ctxP[((size_t)sc * 64 + b) * 512 + h];
    X1[b * 1280 + 768 + h] = s;
}

// ---------------------------------------------------------------------------
// Skinny GEMM (M=64) with K-split partials (f32 VALU).
__global__ __launch_bounds__(1024) void k_gemm_cg(const float* __restrict__ X,
        const float* __restrict__ Wkn, float* __restrict__ P) {
    int n0 = blockIdx.x * 64, sp = blockIdx.y;
    int t = threadIdx.x, tc = t & 63, tr = t >> 6;
    __shared__ __align__(16) float As[64 * 68];
    __shared__ __align__(16) float Wc[64 * 68];
    float acc[4] = {0.f, 0.f, 0.f, 0.f};
    for (int c = 0; c < 5; ++c) {
        int k0 = sp * 320 + c * 64;
        __syncthreads();
#pragma unroll
        for (int i = 0; i < 4; ++i) {
            int idx = i * 1024 + t; int row = idx >> 6; int k = idx & 63;
            As[k * 68 + row] = X[row * 1280 + k0 + k];
        }
#pragma unroll
        for (int i = 0; i < 4; ++i) {
            int idx = i * 1024 + t; int k = idx >> 6; int cc = idx & 63;
            Wc[k * 68 + cc] = Wkn[(size_t)(k0 + k) * 512 + n0 + cc];
        }
        __syncthreads();
#pragma unroll 8
        for (int k = 0; k < 64; ++k) {
            float4 a = *(const float4*)&As[k * 68 + 4 * tr];
            float wv = Wc[k * 68 + tc];
            acc[0] += a.x * wv; acc[1] += a.y * wv; acc[2] += a.z * wv; acc[3] += a.w * wv;
        }
    }
    float* Pp = P + (size_t)sp * 64 * 512;
#pragma unroll
    for (int j = 0; j < 4; ++j) Pp[(4 * tr + j) * 512 + n0 + tc] = acc[j];
}

__global__ __launch_bounds__(1024) void k_gemm_lstm(const float* __restrict__ X, int ldx,
        const float* __restrict__ W1, int K1, const float* __restrict__ W2, int K2,
        int kchunks, float* __restrict__ P) {
    int n0 = blockIdx.x * 64, sp = blockIdx.y;
    int t = threadIdx.x, tc = t & 63, tr = t >> 6;
    __shared__ __align__(16) float As[64 * 68];
    __shared__ __align__(16) float Wc[64 * 68];
    float acc[4] = {0.f, 0.f, 0.f, 0.f};
    for (int c = 0; c < kchunks; ++c) {
        int k0 = (sp * kchunks + c) * 64;
        __syncthreads();
#pragma unroll
        for (int i = 0; i < 4; ++i) {
            int idx = i * 1024 + t; int row = idx >> 6; int k = idx & 63;
            As[k * 68 + row] = X[row * ldx + k0 + k];
        }
#pragma unroll
        for (int i = 0; i < 4; ++i) {
            int idx = i * 1024 + t; int cc = idx >> 6; int k = idx & 63;
            int gk = k0 + k; int j = n0 + cc;
            float wv = (gk < K1) ? W1[(size_t)j * K1 + gk] : W2[(size_t)j * K2 + gk - K1];
            Wc[k * 68 + cc] = wv;
        }
        __syncthreads();
#pragma unroll 8
        for (int k = 0; k < 64; ++k) {
            float4 a = *(const float4*)&As[k * 68 + 4 * tr];
            float wv = Wc[k * 68 + tc];
            acc[0] += a.x * wv; acc[1] += a.y * wv; acc[2] += a.z * wv; acc[3] += a.w * wv;
        }
    }
    float* Pp = P + (size_t)sp * 64 * 2048;
#pragma unroll
    for (int j = 0; j < 4; ++j) Pp[(4 * tr + j) * 2048 + n0 + tc] = acc[j];
}

// ---------------------------------------------------------------------------
__global__ void k_cg_fin(const float* __restrict__ P, const float* __restrict__ cg_b,
                         const float* __restrict__ X1, float* __restrict__ X2) {
    int idx = blockIdx.x * 256 + threadIdx.x;
    int b = idx >> 9, h = idx & 511;
    float g = cg_b[h];
#pragma unroll
    for (int sp = 0; sp < 4; ++sp) g += P[sp * 32768 + idx];
    float gate = sigf(g);
    X2[b * 1280 + 256 + h] = gate * X1[b * 1280 + 768 + h];
}

__global__ void k_lstm_fin(const float* __restrict__ P, const float* __restrict__ bih,
                           const float* __restrict__ bhh, const float* __restrict__ c0,
                           int layer, float* __restrict__ oh, float* __restrict__ oc,
                           float* __restrict__ X3out) {
    int idx = blockIdx.x * 256 + threadIdx.x;
    int b = idx >> 9, h = idx & 511;
    float gi = bih[h] + bhh[h];
    float gf = bih[512 + h] + bhh[512 + h];
    float gg = bih[1024 + h] + bhh[1024 + h];
    float go = bih[1536 + h] + bhh[1536 + h];
#pragma unroll
    for (int sp = 0; sp < 4; ++sp) {
        const float* Pp = P + sp * 131072 + b * 2048;
        gi += Pp[h]; gf += Pp[512 + h]; gg += Pp[1024 + h]; go += Pp[1536 + h];
    }
    float cp = c0[layer * 32768 + b * 512 + h];
    float cn = sigf(gf) * cp + sigf(gi) * tanhf(gg);
    float hn = sigf(go) * tanhf(cn);
    oh[b * 512 + h] = hn;
    oc[b * 512 + h] = cn;
    if (X3out) X3out[b * 1024 + h] = hn;
}

// ---------------------------------------------------------------------------
// K5 (MFMA): out = h2 @ out_W + out_b.  Tile 64x128xK512, 4 waves.
// A (h2) staged to LDS bf16 swizzled; B (out_W f32 KN) loaded direct from
// global into fragments (4 rows x 16 consec cols per instr; ct pair covers
// full 128B lines), converted in-register.
__global__ __launch_bounds__(256) void k_outproj_mfma(
        const float* __restrict__ h2, const float* __restrict__ out_W,
        const float* __restrict__ out_b, float* __restrict__ out) {
    int t = threadIdx.x;
    int n0 = blockIdx.x * 128;
    int w = t >> 6, l = t & 63, li = l & 15, lg = l >> 4;
    int sw = (li & 7) << 4;
    __shared__ __align__(16) unsigned short sA[4096];  // 64 rows x 64 k bf16

    f32x4 acc[4][2];
#pragma unroll
    for (int rt = 0; rt < 4; ++rt)
#pragma unroll
        for (int ct = 0; ct < 2; ++ct) acc[rt][ct] = (f32x4){0.f, 0.f, 0.f, 0.f};
    int colbase = n0 + w * 32;

    for (int kk = 0; kk < 512; kk += 64) {
        __syncthreads();
#pragma unroll
        for (int i = 0; i < 2; ++i) {
            int idx = i * 256 + t, row = idx >> 3, kg = idx & 7;
            const float* g = h2 + row * 512 + kk + kg * 8;
            float4 p0 = *(const float4*)g;
            float4 p1 = *(const float4*)(g + 4);
            uint4 wv;
            wv.x = f2bf(p0.x) | ((unsigned)f2bf(p0.y) << 16);
            wv.y = f2bf(p0.z) | ((unsigned)f2bf(p0.w) << 16);
            wv.z = f2bf(p1.x) | ((unsigned)f2bf(p1.y) << 16);
            wv.w = f2bf(p1.z) | ((unsigned)f2bf(p1.w) << 16);
            int byte = (row * 128 + kg * 16) ^ ((row & 7) << 4);
            *(uint4*)((char*)sA + byte) = wv;
        }
        __syncthreads();
#pragma unroll
        for (int ks = 0; ks < 2; ++ks) {
            short8 bf[2];
#pragma unroll
            for (int ct = 0; ct < 2; ++ct) {
                int col = colbase + ct * 16 + li;
                col = (col < 50000) ? col : 49999;
                const float* wp = out_W + (size_t)(kk + ks * 32 + lg * 8) * 50000 + col;
                uint4 qv;
                float v0 = wp[0],          v1 = wp[50000];
                float v2 = wp[2 * 50000],  v3 = wp[3 * 50000];
                float v4 = wp[4 * 50000],  v5 = wp[5 * 50000];
                float v6 = wp[6 * 50000],  v7 = wp[7 * 50000];
                qv.x = f2bf(v0) | ((unsigned)f2bf(v1) << 16);
                qv.y = f2bf(v2) | ((unsigned)f2bf(v3) << 16);
                qv.z = f2bf(v4) | ((unsigned)f2bf(v5) << 16);
                qv.w = f2bf(v6) | ((unsigned)f2bf(v7) << 16);
                bf[ct] = *(short8*)&qv;
            }
            short8 af[4];
#pragma unroll
            for (int rt = 0; rt < 4; ++rt) {
                int row = rt * 16 + li;
                af[rt] = *(short8*)((char*)sA + ((row * 128 + ks * 64 + lg * 16) ^ sw));
            }
#pragma unroll
            for (int rt = 0; rt < 4; ++rt)
#pragma unroll
                for (int ct = 0; ct < 2; ++ct)
                    acc[rt][ct] = __builtin_amdgcn_mfma_f32_16x16x32_bf16(
                        af[rt], bf[ct], acc[rt][ct], 0, 0, 0);
        }
    }
#pragma unroll
    for (int ct = 0; ct < 2; ++ct) {
        int col = colbase + ct * 16 + li;
        if (col < 50000) {
            float bias = out_b[col];
#pragma unroll
            for (int rt = 0; rt < 4; ++rt)
#pragma unroll
                for (int r = 0; r < 4; ++r) {
                    int row = rt * 16 + lg * 4 + r;
                    out[(size_t)row * 50000 + col] = acc[rt][ct][r] + bias;
                }
        }
    }
}

// ---------------------------------------------------------------------------
extern "C" void kernel_launch(void* const* d_in, const int* in_sizes, int n_in,
                              void* d_out, int out_size, void* d_ws, size_t ws_size,
                              hipStream_t stream) {
    const int*   cur       = (const int*)d_in[0];
    const float* h0        = (const float*)d_in[1];
    const float* c0        = (const float*)d_in[2];
    const float* enc       = (const float*)d_in[3];
    const float* mask      = (const float*)d_in[4];
    const float* emb_table = (const float*)d_in[5];
    const float* attn_W    = (const float*)d_in[6];
    const float* attn_v    = (const float*)d_in[7];
    const float* cg_W      = (const float*)d_in[8];
    const float* cg_b      = (const float*)d_in[9];
    const float* Wih0      = (const float*)d_in[10];
    const float* Whh0      = (const float*)d_in[11];
    const float* bih0      = (const float*)d_in[12];
    const float* bhh0      = (const float*)d_in[13];
    const float* Wih1      = (const float*)d_in[14];
    const float* Whh1      = (const float*)d_in[15];
    const float* bih1      = (const float*)d_in[16];
    const float* bhh1      = (const float*)d_in[17];
    const float* out_W     = (const float*)d_in[18];
    const float* out_b     = (const float*)d_in[19];
    float* out = (float*)d_out;

    float* w    = (float*)d_ws;
    float* X1   = w;                  // 64*1280
    float* X2   = X1 + 81920;         // 64*1280
    float* X3   = X2 + 81920;         // 64*1024
    float* decW = X3 + 65536;         // 64*256
    float* eb   = decW + 16384;       // 64*1024  e scores [b][s], alpha in-place
    float* P    = eb + 65536;         // 4*64*2048 floats
    // Wt (bf16 256x512 = 256KB) parked at P[0..65536 floats) — consumed by
    // k_scores before gemm_cg writes P.  ctxP at P+65536 — consumed by
    // k_ctx_reduce before gemm_cg writes P (stream-serialized).
    unsigned short* Wt = (unsigned short*)P;
    float* ctxP = P + 65536;          // 8*64*512 = 262144 floats

    float* outH = out + 3200000;      // h1 then h2
    float* outC = out + 3265536;      // c1 then c2

    hipLaunchKernelGGL(k_convW, dim3(8, 4), dim3(256), 0, stream, attn_W, Wt);
    hipLaunchKernelGGL(k_prep, dim3(64), dim3(256), 0, stream,
                       cur, h0, emb_table, attn_W, X1, X2, X3, decW);
    hipLaunchKernelGGL(k_scores_mfma, dim3(1024), dim3(256), 0, stream,
                       enc, Wt, attn_v, decW, eb);
    hipLaunchKernelGGL(k_softmax, dim3(64), dim3(256), 0, stream, eb, mask);
    hipLaunchKernelGGL(k_ctx_partial, dim3(512), dim3(512), 0, stream, eb, enc, ctxP);
    hipLaunchKernelGGL(k_ctx_reduce, dim3(128), dim3(256), 0, stream, ctxP, X1);
    hipLaunchKernelGGL(k_gemm_cg, dim3(8, 4), dim3(1024), 0, stream, X1, cg_W, P);
    hipLaunchKernelGGL(k_cg_fin, dim3(128), dim3(256), 0, stream, P, cg_b, X1, X2);
    hipLaunchKernelGGL(k_gemm_lstm, dim3(32, 4), dim3(1024), 0, stream,
                       X2, 1280, Wih0, 768, Whh0, 512, 5, P);
    hipLaunchKernelGGL(k_lstm_fin, dim3(128), dim3(256), 0, stream,
                       P, bih0, bhh0, c0, 0, outH, outC, X3);
    hipLaunchKernelGGL(k_gemm_lstm, dim3(32, 4), dim3(1024), 0, stream,
                       X3, 1024, Wih1, 512, Whh1, 512, 4, P);
    hipLaunchKernelGGL(k_lstm_fin, dim3(128), dim3(256), 0, stream,
                       P, bih1, bhh1, c0, 1, outH + 32768, outC + 32768, (float*)nullptr);
    hipLaunchKernelGGL(k_outproj_mfma, dim3(391), dim3(256), 0, stream,
                       outH + 32768, out_W, out_b, out);
}